// Round 8
// baseline (65.524 us; speedup 1.0000x reference)
//
#include <hip/hip_runtime.h>

#define TT 1024
#define FF 512
#define BB 32

typedef float f32x4 __attribute__((ext_vector_type(4)));

__device__ __forceinline__ void nt_store4(float* p, f32x4 v) {
    __builtin_nontemporal_store(v, (f32x4*)p);
}

// ---------------- Kernel 1: ws[b,t] = sigmoid(x[b,t,:] . w + bias) ----------
// One wave per row; lane i handles 8 contiguous floats. Double accumulation:
// closest-to-exact dot -> minimizes strict-< valley tie flips vs numpy ref.
// At the 64 MB cold-read HBM floor (~10 us). PROVEN — do not touch.
__global__ __launch_bounds__(256) void gate_kernel(const float* __restrict__ x,
                                                   const float* __restrict__ w,
                                                   const float* __restrict__ bias,
                                                   float* __restrict__ ws) {
    int wid  = threadIdx.x >> 6;
    int lane = threadIdx.x & 63;
    int row  = blockIdx.x * 4 + wid;              // 0 .. 32767
    const float4* xr = (const float4*)(x + (size_t)row * FF);
    const float4* wr = (const float4*)w;
    float4 x0 = xr[lane * 2],     x1 = xr[lane * 2 + 1];
    float4 w0 = wr[lane * 2],     w1 = wr[lane * 2 + 1];
    double acc = (double)x0.x * w0.x + (double)x0.y * w0.y +
                 (double)x0.z * w0.z + (double)x0.w * w0.w +
                 (double)x1.x * w1.x + (double)x1.y * w1.y +
                 (double)x1.z * w1.z + (double)x1.w * w1.w;
    #pragma unroll
    for (int off = 32; off; off >>= 1) acc += __shfl_down(acc, off);
    if (lane == 0) {
        float z = (float)acc + bias[0];
        ws[row] = 1.0f / (1.0f + expf(-z));
    }
}

// ---- Kernel 2: fused segmentation + segment means + mask -------------------
// Main blocks (bid<8192): R4's proven per-wave segment-mean structure, but the
// per-batch segmentation (valley ranks, prefix sums, den) is recomputed
// IN-BLOCK from ws (4KB, L2-hot) instead of a separate 32-block kernel.
// Upper-half blocks (s>=512, block-uniform) exit to zero-fill BEFORE any
// barrier. Trailing 32 blocks (bid>=8192) self-compute all-batch counts and
// write the new_mask rows (latency hidden under the main wall).
__global__ __launch_bounds__(256) void out_fused(const float* __restrict__ x,
                                                 const float* __restrict__ ws,
                                                 const int* __restrict__ seq,
                                                 float* __restrict__ out) {
    int bid   = blockIdx.x;
    int tid   = threadIdx.x;
    int wavid = tid >> 6;
    int lane  = tid & 63;

    __shared__ float wsh[TT];          // ws row of this block's batch
    __shared__ float psm[TT];          // inclusive prefix of ws
    __shared__ int   sval[512];        // valley rank -> position
    __shared__ int   wsi[4];
    __shared__ float wsf[4];
    __shared__ float wrow[TT];         // mask path scratch
    __shared__ int   redc[4];

    if (bid >= 8192) {                 // ---- 32 mask blocks
        int bb = bid - 8192;
        int maxc = 0;
        for (int b2 = 0; b2 < BB; ++b2) {
            ((f32x4*)wrow)[tid] = ((const f32x4*)(ws + b2 * TT))[tid];
            __syncthreads();
            int c = 0;
            #pragma unroll
            for (int k = 0; k < 4; ++k) {
                int t = tid * 4 + k;
                if (t > 0 && t < TT - 1) {
                    float w = wrow[t];
                    c += (w < wrow[t - 1] && w < wrow[t + 1]) ? 1 : 0;
                }
            }
            #pragma unroll
            for (int off = 32; off; off >>= 1) c += __shfl_down(c, off);
            if (lane == 0) redc[wavid] = c;
            __syncthreads();
            int cnt = redc[0] + redc[1] + redc[2] + redc[3] + 1;
            maxc = max(maxc, cnt);
        }
        float l0 = (float)seq[0];
        float v  = ((float)seq[bb] / l0) * (float)maxc;   // match jnp f32 order
        int nl = (int)v;                                  // trunc like astype
        float* mrow = out + (size_t)BB * TT * FF + (size_t)bb * TT;
        int s4 = tid * 4;
        f32x4 mv;
        mv.x = (s4 + 0 < nl) ? 1.0f : 0.0f;
        mv.y = (s4 + 1 < nl) ? 1.0f : 0.0f;
        mv.z = (s4 + 2 < nl) ? 1.0f : 0.0f;
        mv.w = (s4 + 3 < nl) ? 1.0f : 0.0f;
        nt_store4(mrow + s4, mv);
        return;
    }

    // XCD-aware bijective swizzle (8192 blocks): XCD k owns 4 contiguous
    // batches -> overlapping segment reads hit its own L2.
    int swz = (bid & 7) * 1024 + (bid >> 3);
    int bs  = swz * 4 + wavid;         // b*1024 + s (block = 4 consecutive s)
    int b   = bs >> 10;
    int s   = bs & 1023;
    float* orow = out + (size_t)bs * FF + lane * 8;
    int qs = (swz * 4) & 1023;         // block-uniform quad start within batch

    if (qs >= 512) {                   // upper half: counts<=512 -> always zero
        f32x4 z = 0.0f;                // (uniform exit BEFORE any barrier)
        nt_store4(orow, z);
        nt_store4(orow + 4, z);
        return;
    }

    // ---- in-block segmentation of batch b (replaces the old seg_kernel)
    const float* wsr = ws + b * TT;
    f32x4 w4 = ((const f32x4*)wsr)[tid];
    ((f32x4*)wsh)[tid] = w4;
    __syncthreads();

    int t0 = tid * 4;
    unsigned flags = 0; int nv = 0;
    #pragma unroll
    for (int k = 0; k < 4; ++k) {
        int t = t0 + k;
        bool vly = false;
        if (t > 0 && t < TT - 1) {
            float w = wsh[t];
            vly = (w < wsh[t - 1]) && (w < wsh[t + 1]);
        }
        flags |= (vly ? 1u : 0u) << k;
        nv += vly ? 1 : 0;
    }
    float ts = w4.x + w4.y + w4.z + w4.w;
    int iscan = nv; float fscan = ts;   // inclusive wave scans
    #pragma unroll
    for (int off = 1; off < 64; off <<= 1) {
        int   vi = __shfl_up(iscan, off);
        float vf = __shfl_up(fscan, off);
        if (lane >= off) { iscan += vi; fscan += vf; }
    }
    if (lane == 63) { wsi[wavid] = iscan; wsf[wavid] = fscan; }
    __syncthreads();
    int ibase = 0; float fbase = 0.0f;
    for (int w2 = 0; w2 < wavid; ++w2) { ibase += wsi[w2]; fbase += wsf[w2]; }
    int   r   = ibase + iscan - nv;     // exclusive valley-rank base
    float run = fbase + fscan - ts;     // exclusive ws-prefix before t0
    #pragma unroll
    for (int k = 0; k < 4; ++k)
        if ((flags >> k) & 1u) sval[r++] = t0 + k;
    #pragma unroll
    for (int k = 0; k < 4; ++k) { run += wsh[t0 + k]; psm[t0 + k] = run; }
    __syncthreads();
    int totv = wsi[0] + wsi[1] + wsi[2] + wsi[3];
    int cnt  = totv + 1;

    // ---- per-wave segment mean (R4's proven 8-row clamped unroll)
    if (s < cnt) {
        int st = (s == 0)    ? 0  : sval[s - 1];
        int en = (s == totv) ? TT : (sval[s] + 2);   // sval<=1022 -> en<=1024
        float d   = psm[en - 1] - (st > 0 ? psm[st - 1] : 0.0f);
        float inv = 1.0f / fmaxf(d, 1e-6f);
        const float* xb = x + (size_t)b * TT * FF + lane * 8;
        f32x4 a0 = 0.0f, a1 = 0.0f;
        #pragma unroll
        for (int k = 0; k < 8; ++k) {
            int t  = st + k;
            int tc = t < en ? t : en - 1;   // clamp: duplicate load, L1-hit
            float wt = t < en ? wsh[tc] : 0.0f;
            const f32x4* xr = (const f32x4*)(xb + (size_t)tc * FF);
            a0 += wt * xr[0];
            a1 += wt * xr[1];
        }
        for (int t = st + 8; t < en; ++t) {  // rare tail (len > 8)
            float wt = wsh[t];
            const f32x4* xr = (const f32x4*)(xb + (size_t)t * FF);
            a0 += wt * xr[0];
            a1 += wt * xr[1];
        }
        nt_store4(orow,     a0 * inv);
        nt_store4(orow + 4, a1 * inv);
    } else {                            // dead rows below 512
        f32x4 z = 0.0f;
        nt_store4(orow, z);
        nt_store4(orow + 4, z);
    }
}

extern "C" void kernel_launch(void* const* d_in, const int* in_sizes, int n_in,
                              void* d_out, int out_size, void* d_ws, size_t ws_size,
                              hipStream_t stream) {
    const float* x   = (const float*)d_in[0];
    const float* aw  = (const float*)d_in[1];
    const float* ab  = (const float*)d_in[2];
    const int*   seq = (const int*)d_in[3];
    float* out = (float*)d_out;

    float* ws = (float*)d_ws;          // ws[32768] is the only workspace use

    gate_kernel<<<BB * TT / 4, 256, 0, stream>>>(x, aw, ab, ws);
    out_fused<<<8192 + 32, 256, 0, stream>>>(x, ws, seq, out);
}

// Round 9
// 42.823 us; speedup vs baseline: 1.5301x; 1.5301x over previous
//
#include <hip/hip_runtime.h>

#define TT 1024
#define FF 512
#define BB 32
#define MAXSEG 513   // valleys are never adjacent -> cnt <= 512

typedef float f32x4 __attribute__((ext_vector_type(4)));

__device__ __forceinline__ void nt_store4(float* p, f32x4 v) {
    __builtin_nontemporal_store(v, (f32x4*)p);
}

// ---------------- Kernel 1: ws[b,t] = sigmoid(x[b,t,:] . w + bias) ----------
// One wave per row; lane i handles 8 contiguous floats. Double accumulation:
// closest-to-exact dot -> minimizes strict-< valley tie flips vs numpy ref.
// At the 64 MB cold-read HBM floor (~10 us). PROVEN — do not touch.
__global__ __launch_bounds__(256) void gate_kernel(const float* __restrict__ x,
                                                   const float* __restrict__ w,
                                                   const float* __restrict__ bias,
                                                   float* __restrict__ ws) {
    int wid  = threadIdx.x >> 6;
    int lane = threadIdx.x & 63;
    int row  = blockIdx.x * 4 + wid;              // 0 .. 32767
    const float4* xr = (const float4*)(x + (size_t)row * FF);
    const float4* wr = (const float4*)w;
    float4 x0 = xr[lane * 2],     x1 = xr[lane * 2 + 1];
    float4 w0 = wr[lane * 2],     w1 = wr[lane * 2 + 1];
    double acc = (double)x0.x * w0.x + (double)x0.y * w0.y +
                 (double)x0.z * w0.z + (double)x0.w * w0.w +
                 (double)x1.x * w1.x + (double)x1.y * w1.y +
                 (double)x1.z * w1.z + (double)x1.w * w1.w;
    #pragma unroll
    for (int off = 32; off; off >>= 1) acc += __shfl_down(acc, off);
    if (lane == 0) {
        float z = (float)acc + bias[0];
        ws[row] = 1.0f / (1.0f + expf(-z));
    }
}

// ---------------- Kernel 2: per-batch valley detect + segment build ---------
// 32 blocks x 1024 threads; fully parallel rank/prefix construction. ~3.5 us
// (latency-bound, small). PROVEN.
__global__ __launch_bounds__(1024) void seg_kernel(const float* __restrict__ ws,
                                                   int* __restrict__ seg_start,
                                                   int* __restrict__ seg_end,
                                                   float* __restrict__ den,
                                                   int* __restrict__ counts) {
    int b = blockIdx.x, t = threadIdx.x;
    __shared__ float w[TT];
    __shared__ float p[TT];
    __shared__ unsigned long long words[16];
    __shared__ float wavesum[16];
    __shared__ int sst[MAXSEG];
    __shared__ int sen[MAXSEG];

    w[t] = ws[b * TT + t];
    __syncthreads();

    float wt = w[t];
    bool valley = (t > 0) && (t < TT - 1) && (wt < w[t - 1]) && (wt < w[t + 1]);
    unsigned long long m = __ballot(valley);
    int wid = t >> 6, lane = t & 63;
    if (lane == 0) words[wid] = m;

    float s = wt;
    #pragma unroll
    for (int off = 1; off < 64; off <<= 1) {
        float v = __shfl_up(s, off);
        if (lane >= off) s += v;
    }
    if (lane == 63) wavesum[wid] = s;
    __syncthreads();

    float offset = 0.0f;
    for (int i = 0; i < wid; ++i) offset += wavesum[i];
    p[t] = s + offset;                     // inclusive prefix over the row

    int before = __popcll(m & ((1ull << lane) - 1ull));
    int total = 0;
    for (int i = 0; i < 16; ++i) {
        int pc = __popcll(words[i]);
        if (i < wid) before += pc;
        total += pc;
    }
    if (valley) {
        int en = t + 2; if (en > TT) en = TT;
        sst[before + 1] = t;               // start of segment rank+1
        sen[before]     = en;              // end of segment rank
    }
    if (t == 0) {
        sst[0]     = 0;
        sen[total] = TT;
        counts[b]  = total + 1;
    }
    __syncthreads();

    int cnt = total + 1;
    if (t < cnt) {
        int st = sst[t], en = sen[t];
        seg_start[b * TT + t] = st;
        seg_end  [b * TT + t] = en;
        float d = p[en - 1] - (st > 0 ? p[st - 1] : 0.0f);
        den[b * TT + t] = fmaxf(d, 1e-6f);
    }
}

// ---------------- Kernel 3: out[b,s,:] = sum_t ws*x / den  (+ mask) ---------
// R4 structure (best known). One wave per output row; XCD-swizzled blocks;
// branch-free 8-row clamped unroll with loads hoisted into temporaries
// before the FMA chain; nontemporal stores.
__global__ __launch_bounds__(256) void out_kernel(const float* __restrict__ x,
                                                  const float* __restrict__ ws,
                                                  const int* __restrict__ seg_start,
                                                  const int* __restrict__ seg_end,
                                                  const float* __restrict__ den,
                                                  const int* __restrict__ counts,
                                                  const int* __restrict__ seq,
                                                  float* __restrict__ out) {
    int bid = blockIdx.x;

    // ---- fused new_mask: 32 designated blocks write the [B,T] mask
    if ((bid & 255) == 0) {
        int bb = bid >> 8;
        int maxc = 0;
        #pragma unroll
        for (int i = 0; i < BB; ++i) maxc = max(maxc, counts[i]);
        float l0 = (float)seq[0];
        float v  = ((float)seq[bb] / l0) * (float)maxc;   // match jnp f32 order
        int nl = (int)v;                                  // trunc like astype
        float* mrow = out + (size_t)BB * TT * FF + (size_t)bb * TT;
        int s4 = threadIdx.x * 4;
        f32x4 mv;
        mv.x = (s4 + 0 < nl) ? 1.0f : 0.0f;
        mv.y = (s4 + 1 < nl) ? 1.0f : 0.0f;
        mv.z = (s4 + 2 < nl) ? 1.0f : 0.0f;
        mv.w = (s4 + 3 < nl) ? 1.0f : 0.0f;
        nt_store4(mrow + s4, mv);
    }

    // XCD-aware bijective swizzle: 8192 blocks, 8 XCDs -> XCD k gets the
    // contiguous swz range [k*1024, (k+1)*1024) = 4 batches.
    int swz = (bid & 7) * 1024 + (bid >> 3);

    int wid  = threadIdx.x >> 6;
    int lane = threadIdx.x & 63;
    int bs = swz * 4 + wid;               // b*1024 + s
    int b  = bs >> 10;
    int s  = bs & 1023;
    float* orow = out + (size_t)bs * FF + lane * 8;
    if (s >= counts[b]) {                 // zero-filled unused segment rows
        f32x4 z = 0.0f;
        nt_store4(orow, z);
        nt_store4(orow + 4, z);
        return;
    }
    int st = seg_start[bs], en = seg_end[bs];
    float inv = 1.0f / den[bs];
    const float* xb  = x + (size_t)b * TT * FF + lane * 8;
    const float* wsr = ws + b * TT;

    // hoist all 8 clamped rows into temporaries (independent loads first)
    int   tci[8];
    float wv[8];
    #pragma unroll
    for (int k = 0; k < 8; ++k) {
        int t  = st + k;
        tci[k] = t < en ? t : en - 1;     // clamp: duplicate load, L1-hit
        wv[k]  = t < en ? wsr[tci[k]] : 0.0f;
    }
    f32x4 r0[8], r1[8];
    #pragma unroll
    for (int k = 0; k < 8; ++k) {
        const f32x4* xr = (const f32x4*)(xb + (size_t)tci[k] * FF);
        r0[k] = xr[0];
        r1[k] = xr[1];
    }
    f32x4 a0 = 0.0f, a1 = 0.0f;
    #pragma unroll
    for (int k = 0; k < 8; ++k) {
        a0 += wv[k] * r0[k];
        a1 += wv[k] * r1[k];
    }
    // rare tail (len > 8)
    for (int t = st + 8; t < en; ++t) {
        float wt = wsr[t];
        const f32x4* xr = (const f32x4*)(xb + (size_t)t * FF);
        a0 += wt * xr[0];
        a1 += wt * xr[1];
    }
    nt_store4(orow,     a0 * inv);
    nt_store4(orow + 4, a1 * inv);
}

extern "C" void kernel_launch(void* const* d_in, const int* in_sizes, int n_in,
                              void* d_out, int out_size, void* d_ws, size_t ws_size,
                              hipStream_t stream) {
    const float* x    = (const float*)d_in[0];
    const float* aw   = (const float*)d_in[1];
    const float* ab   = (const float*)d_in[2];
    const int*   seq  = (const int*)d_in[3];
    float* out = (float*)d_out;

    // workspace layout (floats): ws[32768] | den[32768] | sstart[32768] |
    //                            send[32768] | counts[32]
    float* ws     = (float*)d_ws;
    float* den    = ws + BB * TT;
    int*   sstart = (int*)(ws + 2 * BB * TT);
    int*   send   = (int*)(ws + 3 * BB * TT);
    int*   counts = (int*)(ws + 4 * BB * TT);

    gate_kernel<<<BB * TT / 4, 256, 0, stream>>>(x, aw, ab, ws);
    seg_kernel<<<BB, 1024, 0, stream>>>(ws, sstart, send, den, counts);
    out_kernel<<<BB * TT / 4, 256, 0, stream>>>(x, ws, sstart, send, den, counts,
                                                seq, out);
}

// Round 10
// 40.301 us; speedup vs baseline: 1.6259x; 1.0626x over previous
//
#include <hip/hip_runtime.h>

#define TT 1024
#define FF 512
#define BB 32
#define MAXSEG 513   // valleys are never adjacent -> cnt <= 512

typedef float f32x4 __attribute__((ext_vector_type(4)));

__device__ __forceinline__ void nt_store4(float* p, f32x4 v) {
    __builtin_nontemporal_store(v, (f32x4*)p);
}

// ---------------- Kernel 1: ws[b,t] = sigmoid(x[b,t,:] . w + bias) ----------
// One wave per row; lane i handles 8 contiguous floats. Double accumulation:
// closest-to-exact dot -> minimizes strict-< valley tie flips vs numpy ref.
// At the 64 MB cold-read HBM floor (~10 us). PROVEN — do not touch.
__global__ __launch_bounds__(256) void gate_kernel(const float* __restrict__ x,
                                                   const float* __restrict__ w,
                                                   const float* __restrict__ bias,
                                                   float* __restrict__ ws) {
    int wid  = threadIdx.x >> 6;
    int lane = threadIdx.x & 63;
    int row  = blockIdx.x * 4 + wid;              // 0 .. 32767
    const float4* xr = (const float4*)(x + (size_t)row * FF);
    const float4* wr = (const float4*)w;
    float4 x0 = xr[lane * 2],     x1 = xr[lane * 2 + 1];
    float4 w0 = wr[lane * 2],     w1 = wr[lane * 2 + 1];
    double acc = (double)x0.x * w0.x + (double)x0.y * w0.y +
                 (double)x0.z * w0.z + (double)x0.w * w0.w +
                 (double)x1.x * w1.x + (double)x1.y * w1.y +
                 (double)x1.z * w1.z + (double)x1.w * w1.w;
    #pragma unroll
    for (int off = 32; off; off >>= 1) acc += __shfl_down(acc, off);
    if (lane == 0) {
        float z = (float)acc + bias[0];
        ws[row] = 1.0f / (1.0f + expf(-z));
    }
}

// ---------------- Kernel 2: per-batch valley detect + segment build ---------
// 32 blocks x 1024 threads; fully parallel rank/prefix construction. ~3.5 us
// (latency-bound, small). PROVEN.
__global__ __launch_bounds__(1024) void seg_kernel(const float* __restrict__ ws,
                                                   int* __restrict__ seg_start,
                                                   int* __restrict__ seg_end,
                                                   float* __restrict__ den,
                                                   int* __restrict__ counts) {
    int b = blockIdx.x, t = threadIdx.x;
    __shared__ float w[TT];
    __shared__ float p[TT];
    __shared__ unsigned long long words[16];
    __shared__ float wavesum[16];
    __shared__ int sst[MAXSEG];
    __shared__ int sen[MAXSEG];

    w[t] = ws[b * TT + t];
    __syncthreads();

    float wt = w[t];
    bool valley = (t > 0) && (t < TT - 1) && (wt < w[t - 1]) && (wt < w[t + 1]);
    unsigned long long m = __ballot(valley);
    int wid = t >> 6, lane = t & 63;
    if (lane == 0) words[wid] = m;

    float s = wt;
    #pragma unroll
    for (int off = 1; off < 64; off <<= 1) {
        float v = __shfl_up(s, off);
        if (lane >= off) s += v;
    }
    if (lane == 63) wavesum[wid] = s;
    __syncthreads();

    float offset = 0.0f;
    for (int i = 0; i < wid; ++i) offset += wavesum[i];
    p[t] = s + offset;                     // inclusive prefix over the row

    int before = __popcll(m & ((1ull << lane) - 1ull));
    int total = 0;
    for (int i = 0; i < 16; ++i) {
        int pc = __popcll(words[i]);
        if (i < wid) before += pc;
        total += pc;
    }
    if (valley) {
        int en = t + 2; if (en > TT) en = TT;
        sst[before + 1] = t;               // start of segment rank+1
        sen[before]     = en;              // end of segment rank
    }
    if (t == 0) {
        sst[0]     = 0;
        sen[total] = TT;
        counts[b]  = total + 1;
    }
    __syncthreads();

    int cnt = total + 1;
    if (t < cnt) {
        int st = sst[t], en = sen[t];
        seg_start[b * TT + t] = st;
        seg_end  [b * TT + t] = en;
        float d = p[en - 1] - (st > 0 ? p[st - 1] : 0.0f);
        den[b * TT + t] = fmaxf(d, 1e-6f);
    }
}

// ---------------- Kernel 3: out[b,s,:] = sum_t ws*x / den  (+ mask) ---------
// One wave per output row; XCD-swizzled blocks; branch-free 8-row predicated
// unroll (16 loads in flight); nontemporal stores. R4-exact. PROVEN 40.3 us.
__global__ __launch_bounds__(256) void out_kernel(const float* __restrict__ x,
                                                  const float* __restrict__ ws,
                                                  const int* __restrict__ seg_start,
                                                  const int* __restrict__ seg_end,
                                                  const float* __restrict__ den,
                                                  const int* __restrict__ counts,
                                                  const int* __restrict__ seq,
                                                  float* __restrict__ out) {
    int bid = blockIdx.x;

    // ---- fused new_mask: 32 designated blocks write the [B,T] mask
    if ((bid & 255) == 0) {
        int bb = bid >> 8;
        int maxc = 0;
        #pragma unroll
        for (int i = 0; i < BB; ++i) maxc = max(maxc, counts[i]);
        float l0 = (float)seq[0];
        float v  = ((float)seq[bb] / l0) * (float)maxc;   // match jnp f32 order
        int nl = (int)v;                                  // trunc like astype
        float* mrow = out + (size_t)BB * TT * FF + (size_t)bb * TT;
        int s4 = threadIdx.x * 4;
        f32x4 mv;
        mv.x = (s4 + 0 < nl) ? 1.0f : 0.0f;
        mv.y = (s4 + 1 < nl) ? 1.0f : 0.0f;
        mv.z = (s4 + 2 < nl) ? 1.0f : 0.0f;
        mv.w = (s4 + 3 < nl) ? 1.0f : 0.0f;
        nt_store4(mrow + s4, mv);
    }

    // XCD-aware bijective swizzle: 8192 blocks, 8 XCDs -> XCD k gets the
    // contiguous swz range [k*1024, (k+1)*1024) = 4 batches (8 MB window).
    int swz = (bid & 7) * 1024 + (bid >> 3);

    int wid  = threadIdx.x >> 6;
    int lane = threadIdx.x & 63;
    int bs = swz * 4 + wid;               // b*1024 + s
    int b  = bs >> 10;
    int s  = bs & 1023;
    float* orow = out + (size_t)bs * FF + lane * 8;
    if (s >= counts[b]) {                 // zero-filled unused segment rows
        f32x4 z = 0.0f;
        nt_store4(orow, z);
        nt_store4(orow + 4, z);
        return;
    }
    int st = seg_start[bs], en = seg_end[bs];
    float inv = 1.0f / den[bs];
    const float* xb  = x + (size_t)b * TT * FF + lane * 8;
    const float* wsr = ws + b * TT;
    f32x4 a0 = 0.0f, a1 = 0.0f;
    // 8-row predicated unroll: all 16 loads independent, issued up front.
    #pragma unroll
    for (int k = 0; k < 8; ++k) {
        int t  = st + k;
        int tc = t < en ? t : en - 1;     // clamp: safe re-read, L1-hit
        float wt = t < en ? wsr[tc] : 0.0f;
        const f32x4* xr = (const f32x4*)(xb + (size_t)tc * FF);
        a0 += wt * xr[0];
        a1 += wt * xr[1];
    }
    // rare tail (len > 8)
    for (int t = st + 8; t < en; ++t) {
        float wt = wsr[t];
        const f32x4* xr = (const f32x4*)(xb + (size_t)t * FF);
        a0 += wt * xr[0];
        a1 += wt * xr[1];
    }
    nt_store4(orow,     a0 * inv);
    nt_store4(orow + 4, a1 * inv);
}

extern "C" void kernel_launch(void* const* d_in, const int* in_sizes, int n_in,
                              void* d_out, int out_size, void* d_ws, size_t ws_size,
                              hipStream_t stream) {
    const float* x    = (const float*)d_in[0];
    const float* aw   = (const float*)d_in[1];
    const float* ab   = (const float*)d_in[2];
    const int*   seq  = (const int*)d_in[3];
    float* out = (float*)d_out;

    // workspace layout (floats): ws[32768] | den[32768] | sstart[32768] |
    //                            send[32768] | counts[32]
    float* ws     = (float*)d_ws;
    float* den    = ws + BB * TT;
    int*   sstart = (int*)(ws + 2 * BB * TT);
    int*   send   = (int*)(ws + 3 * BB * TT);
    int*   counts = (int*)(ws + 4 * BB * TT);

    gate_kernel<<<BB * TT / 4, 256, 0, stream>>>(x, aw, ab, ws);
    seg_kernel<<<BB, 1024, 0, stream>>>(ws, sstart, send, den, counts);
    out_kernel<<<BB * TT / 4, 256, 0, stream>>>(x, ws, sstart, send, den, counts,
                                                seq, out);
}